// Round 1
// baseline (351.440 us; speedup 1.0000x reference)
//
#include <hip/hip_runtime.h>
#include <stdint.h>

typedef unsigned short u16;
typedef __attribute__((ext_vector_type(8))) short short8;
typedef __attribute__((ext_vector_type(4))) float f32x4;

#define NTRACE 4096
#define TLEN   64
#define ISZ    64
#define HSZ    128
#define NBLK   NTRACE

#define LOG2E     1.44269504088896f
#define TWOLOG2E  2.88539008177793f

__device__ __forceinline__ float bf2f(u16 u) {
  union { uint32_t i; float f; } v; v.i = ((uint32_t)u) << 16; return v.f;
}
__device__ __forceinline__ u16 f2bf(float f) {
  union { float f; uint32_t i; } v; v.f = f;
  uint32_t r = v.i + 0x7fffu + ((v.i >> 16) & 1u);
  return (u16)(r >> 16);
}
// raw v_exp_f32 (= exp2). Scale factors are pre-folded into weights/biases.
__device__ __forceinline__ float fexp2(float x) {
  float r;
  asm("v_exp_f32 %0, %1" : "=v"(r) : "v"(x));
  return r;
}
// tanh(a)*sigmoid(b) given pre-scaled gates:
//   gB = -log2e * b   (sigmoid gate),  gE = 2*log2e * a  (tanh gate)
// = (E-1) / ((E+1)*(1+B)) with E=exp2(gE), B=exp2(gB)
__device__ __forceinline__ float gate2(float gB, float gE) {
  float E = fexp2(gE);
  float B = fexp2(gB);
  return (E - 1.0f) * __builtin_amdgcn_rcpf((E + 1.0f) * (1.0f + B));
}

// ---------------------------------------------------------------------------
// k_prep: f32->bf16 weight conversion with exp2 scale folding, bias sums,
// and emb -> bf16 pre-conversion.
// Row scaling (gate order i,f,g,o): rows [0,256) and [384,512) (sigmoid
// gates) * -log2e ; rows [256,384) (tanh gate) * 2*log2e.
// ---------------------------------------------------------------------------
__global__ __launch_bounds__(256) void k_prep(
    const float* __restrict__ emb,
    const float* __restrict__ W1, const float* __restrict__ W2,
    const float* __restrict__ Wp1,
    const float* __restrict__ b_ih1, const float* __restrict__ b_hh1,
    const float* __restrict__ b_ih2, const float* __restrict__ b_hh2,
    u16* __restrict__ embb,
    u16* __restrict__ w1b, u16* __restrict__ w2b, u16* __restrict__ wp1b,
    float* __restrict__ bs1, float* __restrict__ bs2)
{
  const int i = blockIdx.x * 256 + threadIdx.x;   // 65536 threads
  if (i < 512 * 64) {
    const int r = i >> 6;
    const float s = (r >= 256 && r < 384) ? TWOLOG2E : -LOG2E;
    w1b[i] = f2bf(W1[i] * s);
  }
  if (i < 512 * 128) {
    const int r = i >> 7;
    const float s = (r >= 256 && r < 384) ? TWOLOG2E : -LOG2E;
    w2b[i] = f2bf(W2[i] * s);
  }
  if (i < 64 * 128) wp1b[i] = f2bf(Wp1[i]);
  if (i < 512) {
    const float s = (i >= 256 && i < 384) ? TWOLOG2E : -LOG2E;
    bs1[i] = (b_ih1[i] + b_hh1[i]) * s;
    bs2[i] = (b_ih2[i] + b_hh2[i]) * s;
  }
  for (int j = i; j < 10000 * 64; j += 256 * 256) embb[j] = f2bf(emb[j]);
}

// ---------------------------------------------------------------------------
// k_fused: 1 block (4 waves, 256 thr) per trace; wave g owns token group g.
// Shared h2 buffer (disjoint 16-row slices per wave), ONE barrier, then
// wave0 does softmax + weighted sum.
// hbuf XOR-chunk swizzle: (token,h) -> column ((h>>3)^(token&15))*8 + (h&7).
// ---------------------------------------------------------------------------
__global__ __launch_bounds__(256, 4) void k_fused(
    const u16* __restrict__ embb,
    const u16* __restrict__ w1b, const float* __restrict__ bs1,
    const u16* __restrict__ w2b, const float* __restrict__ bs2,
    const u16* __restrict__ wp1b,
    const float* __restrict__ bp1v, const float* __restrict__ Wp2,
    const float* __restrict__ bp2v,
    const int* __restrict__ traces, const int* __restrict__ lengths,
    float* __restrict__ partials)
{
  __shared__ __align__(16) u16 hbuf[TLEN * HSZ];   // 16 KB: h1 then h2
  __shared__ float ebuf[TLEN];                     // energies
  __shared__ float wbuf[TLEN];                     // softmax weights
  const int t    = blockIdx.x;
  const int len  = lengths[t];
  const int wv   = threadIdx.x >> 6;   // wave id = token group
  const int lane = threadIdx.x & 63;
  const int col  = lane & 15;
  const int q    = lane >> 4;
  const f32x4 z = {0.f, 0.f, 0.f, 0.f};

  if (wv * 16 < len) {                 // wave-uniform: active group
    const int g = wv;

    // ---- x fragments (bf16 emb, B-operand of lstm1)
    const int tok = traces[t * TLEN + g * 16 + col];
    const u16* xr = embb + (size_t)tok * ISZ + q * 8;
    short8 xf[2];
    xf[0] = *(const short8*)(xr);
    xf[1] = *(const short8*)(xr + 32);

    // ---- LSTM layer 1 (K=64); gate rows i@0, g@256, o@384
#pragma unroll
    for (int mt = 0; mt < 8; ++mt) {
      f32x4 aI = z, aC = z, aO = z;
#pragma unroll
      for (int ks = 0; ks < 2; ++ks) {
        const u16* wb = w1b + ks * 32 + q * 8;
        short8 fI = *(const short8*)(wb + (size_t)(mt * 16 + col) * ISZ);
        short8 fC = *(const short8*)(wb + (size_t)(256 + mt * 16 + col) * ISZ);
        short8 fO = *(const short8*)(wb + (size_t)(384 + mt * 16 + col) * ISZ);
        aI = __builtin_amdgcn_mfma_f32_16x16x32_bf16(fI, xf[ks], aI, 0, 0, 0);
        aC = __builtin_amdgcn_mfma_f32_16x16x32_bf16(fC, xf[ks], aC, 0, 0, 0);
        aO = __builtin_amdgcn_mfma_f32_16x16x32_bf16(fO, xf[ks], aO, 0, 0, 0);
      }
      const int hbase = mt * 16 + q * 4;
      const int wcol = ((mt * 2 + (q >> 1)) ^ col) * 8 + (q & 1) * 4;
      u16 hv[4];
#pragma unroll
      for (int r = 0; r < 4; ++r) {
        const int h = hbase + r;
        float c = gate2(aI[r] + bs1[h], aC[r] + bs1[256 + h]);
        hv[r] = f2bf(gate2(aO[r] + bs1[384 + h], TWOLOG2E * c));
      }
      uint2 pk;
      pk.x = (uint32_t)hv[0] | ((uint32_t)hv[1] << 16);
      pk.y = (uint32_t)hv[2] | ((uint32_t)hv[3] << 16);
      *(uint2*)&hbuf[(g * 16 + col) * HSZ + wcol] = pk;
    }
    asm volatile("s_waitcnt lgkmcnt(0)" ::: "memory");

    // ---- h1 fragments (B-operand of lstm2), swizzled reads (own rows only)
    short8 hf[4];
#pragma unroll
    for (int ks = 0; ks < 4; ++ks)
      hf[ks] = *(const short8*)&hbuf[(g * 16 + col) * HSZ + ((ks * 4 + q) ^ col) * 8];
    asm volatile("s_waitcnt lgkmcnt(0)" ::: "memory");

    // ---- LSTM layer 2 (K=128)
#pragma unroll
    for (int mt = 0; mt < 8; ++mt) {
      f32x4 aI = z, aC = z, aO = z;
#pragma unroll
      for (int ks = 0; ks < 4; ++ks) {
        const u16* wb = w2b + ks * 32 + q * 8;
        short8 fI = *(const short8*)(wb + (size_t)(mt * 16 + col) * HSZ);
        short8 fC = *(const short8*)(wb + (size_t)(256 + mt * 16 + col) * HSZ);
        short8 fO = *(const short8*)(wb + (size_t)(384 + mt * 16 + col) * HSZ);
        aI = __builtin_amdgcn_mfma_f32_16x16x32_bf16(fI, hf[ks], aI, 0, 0, 0);
        aC = __builtin_amdgcn_mfma_f32_16x16x32_bf16(fC, hf[ks], aC, 0, 0, 0);
        aO = __builtin_amdgcn_mfma_f32_16x16x32_bf16(fO, hf[ks], aO, 0, 0, 0);
      }
      const int hbase = mt * 16 + q * 4;
      const int wcol = ((mt * 2 + (q >> 1)) ^ col) * 8 + (q & 1) * 4;
      u16 hv[4];
#pragma unroll
      for (int r = 0; r < 4; ++r) {
        const int h = hbase + r;
        float c = gate2(aI[r] + bs2[h], aC[r] + bs2[256 + h]);
        hv[r] = f2bf(gate2(aO[r] + bs2[384 + h], TWOLOG2E * c));
      }
      uint2 pk;
      pk.x = (uint32_t)hv[0] | ((uint32_t)hv[1] << 16);
      pk.y = (uint32_t)hv[2] | ((uint32_t)hv[3] << 16);
      *(uint2*)&hbuf[(g * 16 + col) * HSZ + wcol] = pk;
    }
    asm volatile("s_waitcnt lgkmcnt(0)" ::: "memory");

    // ---- reload fragments: now h2
#pragma unroll
    for (int ks = 0; ks < 4; ++ks)
      hf[ks] = *(const short8*)&hbuf[(g * 16 + col) * HSZ + ((ks * 4 + q) ^ col) * 8];

    // ---- attention-MLP energy for this group's 16 tokens
    float ep = 0.f;
#pragma unroll
    for (int mt = 0; mt < 4; ++mt) {
      f32x4 acc = z;
#pragma unroll
      for (int ks = 0; ks < 4; ++ks) {
        short8 fA = *(const short8*)(wp1b + (size_t)(mt * 16 + col) * HSZ + ks * 32 + q * 8);
        acc = __builtin_amdgcn_mfma_f32_16x16x32_bf16(fA, hf[ks], acc, 0, 0, 0);
      }
#pragma unroll
      for (int r = 0; r < 4; ++r) {
        const int hp = mt * 16 + q * 4 + r;
        ep += fmaxf(acc[r] + bp1v[hp], 0.f) * Wp2[hp];
      }
    }
    ep += __shfl_xor(ep, 16);
    ep += __shfl_xor(ep, 32);
    if (q == 0) ebuf[g * 16 + col] = ep + bp2v[0];
  }

  __syncthreads();          // h2 + energies visible block-wide
  if (wv != 0) return;      // waves 1..3 done; wave0 finishes the trace

  // ---- masked softmax over 64 positions (lane == position)
  const int ngrp = (len + 15) >> 4;
  const bool vld = lane < len;
  const float e = ebuf[lane];
  float m = vld ? e : -3.0e38f;
#pragma unroll
  for (int off = 1; off < 64; off <<= 1) m = fmaxf(m, __shfl_xor(m, off));
  float wgt = vld ? __expf(e - m) : 0.f;
  float s = wgt;
#pragma unroll
  for (int off = 1; off < 64; off <<= 1) s += __shfl_xor(s, off);
  wbuf[lane] = wgt * __builtin_amdgcn_rcpf(s);
  asm volatile("s_waitcnt lgkmcnt(0)" ::: "memory");

  // ---- weighted sum: te[h] = sum_l w[l] * h2[l][h]
  // lane covers h = 4*(lane&31)..+3; positions l = 2*i + (lane>>5)
  const int half = lane >> 5;
  const int hb   = (lane & 31) * 4;
  const int rchunk = hb >> 3;
  float a4[4] = {0.f, 0.f, 0.f, 0.f};
  for (int g2 = 0; g2 < ngrp; ++g2) {
#pragma unroll
    for (int i = 0; i < 8; ++i) {
      const int l = g2 * 16 + 2 * i + half;
      const float wl = wbuf[l];
      const int sw = ((rchunk ^ (l & 15)) * 8) + (hb & 7);
      const uint2 hv = *(const uint2*)&hbuf[l * HSZ + sw];
      a4[0] += wl * bf2f((u16)(hv.x & 0xffffu));
      a4[1] += wl * bf2f((u16)(hv.x >> 16));
      a4[2] += wl * bf2f((u16)(hv.y & 0xffffu));
      a4[3] += wl * bf2f((u16)(hv.y >> 16));
    }
  }
#pragma unroll
  for (int k = 0; k < 4; ++k) a4[k] += __shfl_xor(a4[k], 32);

  if (half == 0) {
    f32x4 st = {a4[0], a4[1], a4[2], a4[3]};
    *(f32x4*)&partials[(size_t)t * HSZ + hb] = st;
  }
}

// ---------------------------------------------------------------------------
// k_reduce: fin[h] = sum over 4096 trace partials
// ---------------------------------------------------------------------------
__global__ __launch_bounds__(256) void k_reduce(
    const float* __restrict__ partials, float* __restrict__ fin)
{
  const int h = blockIdx.x;
  float s = 0.f;
  for (int b = threadIdx.x; b < NBLK; b += 256) s += partials[(size_t)b * HSZ + h];
#pragma unroll
  for (int off = 32; off >= 1; off >>= 1) s += __shfl_xor(s, off);
  __shared__ float part[4];
  if ((threadIdx.x & 63) == 0) part[threadIdx.x >> 6] = s;
  __syncthreads();
  if (threadIdx.x == 0) fin[h] = part[0] + part[1] + part[2] + part[3];
}

// out = final @ W_out.T + b_out   (128x128, one block, FP32)
__global__ __launch_bounds__(128) void k_out(
    const float* __restrict__ fin, const float* __restrict__ W_out,
    const float* __restrict__ b_out, float* __restrict__ out)
{
  const int o = threadIdx.x;
  __shared__ float fs[HSZ];
  fs[o] = fin[o];
  __syncthreads();
  float acc = b_out[o];
  const float* wr = W_out + (size_t)o * HSZ;
#pragma unroll
  for (int h = 0; h < HSZ; ++h) acc += wr[h] * fs[h];
  out[o] = acc;
}

extern "C" void kernel_launch(void* const* d_in, const int* in_sizes, int n_in,
                              void* d_out, int out_size, void* d_ws, size_t ws_size,
                              hipStream_t stream)
{
  const float* emb   = (const float*)d_in[0];
  const float* W_ih1 = (const float*)d_in[1];
  // d_in[2] = W_hh1: unused (h0 = 0)
  const float* b_ih1 = (const float*)d_in[3];
  const float* b_hh1 = (const float*)d_in[4];
  const float* W_ih2 = (const float*)d_in[5];
  // d_in[6] = W_hh2: unused
  const float* b_ih2 = (const float*)d_in[7];
  const float* b_hh2 = (const float*)d_in[8];
  const float* Wp1   = (const float*)d_in[9];
  const float* bp1   = (const float*)d_in[10];
  const float* Wp2   = (const float*)d_in[11];
  const float* bp2   = (const float*)d_in[12];
  const float* W_out = (const float*)d_in[13];
  const float* b_out = (const float*)d_in[14];
  const int* traces  = (const int*)d_in[15];
  const int* lengths = (const int*)d_in[16];

  char* ws = (char*)d_ws;
  u16*   w1b      = (u16*)(ws);                  // 512*64*2   = 65536 B
  u16*   w2b      = (u16*)(ws + 65536);          // 512*128*2  = 131072 B
  u16*   wp1b     = (u16*)(ws + 196608);         // 64*128*2   = 16384 B
  float* bs1      = (float*)(ws + 212992);       // 2048 B
  float* bs2      = (float*)(ws + 215040);       // 2048 B
  float* fin      = (float*)(ws + 217088);       // 512 B
  float* partials = (float*)(ws + 217600);       // 4096*128*4 = 2 MiB
  u16*   embb     = (u16*)(ws + 2314752);        // 10000*64*2 = 1280000 B

  k_prep<<<256, 256, 0, stream>>>(emb, W_ih1, W_ih2, Wp1, b_ih1, b_hh1,
                                  b_ih2, b_hh2, embb, w1b, w2b, wp1b, bs1, bs2);
  k_fused<<<NBLK, 256, 0, stream>>>(embb, w1b, bs1, w2b, bs2, wp1b,
                                    bp1, Wp2, bp2, traces, lengths, partials);
  k_reduce<<<HSZ, 256, 0, stream>>>(partials, fin);
  k_out<<<1, 128, 0, stream>>>(fin, W_out, b_out, (float*)d_out);
}

// Round 2
// 252.568 us; speedup vs baseline: 1.3915x; 1.3915x over previous
//
#include <hip/hip_runtime.h>
#include <stdint.h>

typedef unsigned short u16;
typedef __attribute__((ext_vector_type(8))) short short8;
typedef __attribute__((ext_vector_type(4))) float f32x4;

#define NTRACE 4096
#define TLEN   64
#define ISZ    64
#define HSZ    128
#define NBLK   NTRACE

#define LOG2E     1.44269504088896f
#define TWOLOG2E  2.88539008177793f

__device__ __forceinline__ float bf2f(u16 u) {
  union { uint32_t i; float f; } v; v.i = ((uint32_t)u) << 16; return v.f;
}
__device__ __forceinline__ u16 f2bf(float f) {
  union { float f; uint32_t i; } v; v.f = f;
  uint32_t r = v.i + 0x7fffu + ((v.i >> 16) & 1u);
  return (u16)(r >> 16);
}
// raw v_exp_f32 (= exp2). Scale factors pre-folded into weights/biases.
__device__ __forceinline__ float fexp2(float x) {
  float r;
  asm("v_exp_f32 %0, %1" : "=v"(r) : "v"(x));
  return r;
}
// tanh(a)*sigmoid(b) given pre-scaled gates:
//   gB = -log2e * b  (sigmoid gate),  gE = 2*log2e * a  (tanh gate)
// = (E-1) / ((E+1)*(1+B)) with E=exp2(gE), B=exp2(gB)
__device__ __forceinline__ float gate2(float gB, float gE) {
  float E = fexp2(gE);
  float B = fexp2(gB);
  return (E - 1.0f) * __builtin_amdgcn_rcpf((E + 1.0f) * (1.0f + B));
}

// ---------------------------------------------------------------------------
// k_prep: f32->bf16 weight conversion with exp2 scale folding, bias sums,
// emb -> bf16, fin zero.
// Gate rows (torch order i,f,g,o): [0,256)+[384,512) sigmoid * -log2e ;
// [256,384) tanh * 2*log2e.
// ---------------------------------------------------------------------------
__global__ __launch_bounds__(256) void k_prep(
    const float* __restrict__ emb,
    const float* __restrict__ W1, const float* __restrict__ W2,
    const float* __restrict__ Wp1,
    const float* __restrict__ b_ih1, const float* __restrict__ b_hh1,
    const float* __restrict__ b_ih2, const float* __restrict__ b_hh2,
    u16* __restrict__ embb,
    u16* __restrict__ w1b, u16* __restrict__ w2b, u16* __restrict__ wp1b,
    float* __restrict__ bs1, float* __restrict__ bs2,
    float* __restrict__ fin)
{
  const int i = blockIdx.x * 256 + threadIdx.x;   // 65536 threads
  if (i < 512 * 64) {
    const int r = i >> 6;
    const float s = (r >= 256 && r < 384) ? TWOLOG2E : -LOG2E;
    w1b[i] = f2bf(W1[i] * s);
  }
  if (i < 512 * 128) {
    const int r = i >> 7;
    const float s = (r >= 256 && r < 384) ? TWOLOG2E : -LOG2E;
    w2b[i] = f2bf(W2[i] * s);
  }
  if (i < 64 * 128) wp1b[i] = f2bf(Wp1[i]);
  if (i < 512) {
    const float s = (i >= 256 && i < 384) ? TWOLOG2E : -LOG2E;
    bs1[i] = (b_ih1[i] + b_hh1[i]) * s;
    bs2[i] = (b_ih2[i] + b_hh2[i]) * s;
  }
  if (i < 128) fin[i] = 0.f;
  for (int j = i; j < 10000 * 64; j += 256 * 256) embb[j] = f2bf(emb[j]);
}

// ---------------------------------------------------------------------------
// trace_body<NG>: one wave, one trace, NG = ceil(len/16) active token groups.
// Branch-free per instantiation; weight loads amortized over NG groups.
// hbuf XOR-chunk swizzle: (token,h) -> column ((h>>3)^(token&15))*8 + (h&7).
// ---------------------------------------------------------------------------
template<int NG>
__device__ __forceinline__ void trace_body(
    u16* __restrict__ hbuf,            // [TLEN][HSZ] flat, wave-private
    float* __restrict__ wbuf,          // [TLEN] softmax weights
    const u16* __restrict__ embb,
    const u16* __restrict__ w1b, const float* __restrict__ bs1,
    const u16* __restrict__ w2b, const float* __restrict__ bs2,
    const u16* __restrict__ wp1b,
    const float* __restrict__ bp1v, const float* __restrict__ Wp2,
    const float* __restrict__ bp2v,
    const int* __restrict__ traces,
    float* __restrict__ partials, int t, int len)
{
  const int lane = threadIdx.x & 63;
  const int col  = lane & 15;
  const int q    = lane >> 4;
  const f32x4 z = {0.f, 0.f, 0.f, 0.f};

  // WAR guard: previous trace's LDS reads must land before we overwrite hbuf
  asm volatile("s_waitcnt lgkmcnt(0)" ::: "memory");

  // ---- x fragments (bf16 emb, B-operand of lstm1)
  short8 xf[NG][2];
#pragma unroll
  for (int g = 0; g < NG; ++g) {
    const int tok = traces[t * TLEN + g * 16 + col];
    const u16* xr = embb + (size_t)tok * ISZ + q * 8;
    xf[g][0] = *(const short8*)(xr);
    xf[g][1] = *(const short8*)(xr + 32);
  }

  // ---- LSTM layer 1 (K=64); gate rows i@0, g@256, o@384
#pragma unroll
  for (int mt = 0; mt < 8; ++mt) {
    f32x4 aI[NG], aC[NG], aO[NG];
#pragma unroll
    for (int g = 0; g < NG; ++g) { aI[g] = z; aC[g] = z; aO[g] = z; }
#pragma unroll
    for (int ks = 0; ks < 2; ++ks) {
      const u16* wb = w1b + ks * 32 + q * 8;
      short8 fI = *(const short8*)(wb + (size_t)(mt * 16 + col) * ISZ);
      short8 fC = *(const short8*)(wb + (size_t)(256 + mt * 16 + col) * ISZ);
      short8 fO = *(const short8*)(wb + (size_t)(384 + mt * 16 + col) * ISZ);
#pragma unroll
      for (int g = 0; g < NG; ++g) {
        aI[g] = __builtin_amdgcn_mfma_f32_16x16x32_bf16(fI, xf[g][ks], aI[g], 0, 0, 0);
        aC[g] = __builtin_amdgcn_mfma_f32_16x16x32_bf16(fC, xf[g][ks], aC[g], 0, 0, 0);
        aO[g] = __builtin_amdgcn_mfma_f32_16x16x32_bf16(fO, xf[g][ks], aO[g], 0, 0, 0);
      }
    }
    float bI[4], bC[4], bO[4];
#pragma unroll
    for (int r = 0; r < 4; ++r) {
      const int h = mt * 16 + q * 4 + r;
      bI[r] = bs1[h]; bC[r] = bs1[256 + h]; bO[r] = bs1[384 + h];
    }
    const int wcol = ((mt * 2 + (q >> 1)) ^ col) * 8 + (q & 1) * 4;
#pragma unroll
    for (int g = 0; g < NG; ++g) {
      u16 hv[4];
#pragma unroll
      for (int r = 0; r < 4; ++r) {
        float c = gate2(aI[g][r] + bI[r], aC[g][r] + bC[r]);
        hv[r] = f2bf(gate2(aO[g][r] + bO[r], TWOLOG2E * c));
      }
      uint2 pk;
      pk.x = (uint32_t)hv[0] | ((uint32_t)hv[1] << 16);
      pk.y = (uint32_t)hv[2] | ((uint32_t)hv[3] << 16);
      *(uint2*)&hbuf[(g * 16 + col) * HSZ + wcol] = pk;
    }
  }
  asm volatile("s_waitcnt lgkmcnt(0)" ::: "memory");

  // ---- h1 fragments (B-operand of lstm2), swizzled reads
  short8 hf[NG][4];
#pragma unroll
  for (int g = 0; g < NG; ++g)
#pragma unroll
    for (int ks = 0; ks < 4; ++ks)
      hf[g][ks] = *(const short8*)&hbuf[(g * 16 + col) * HSZ + ((ks * 4 + q) ^ col) * 8];
  asm volatile("s_waitcnt lgkmcnt(0)" ::: "memory");

  // ---- LSTM layer 2 (K=128)
#pragma unroll
  for (int mt = 0; mt < 8; ++mt) {
    f32x4 aI[NG], aC[NG], aO[NG];
#pragma unroll
    for (int g = 0; g < NG; ++g) { aI[g] = z; aC[g] = z; aO[g] = z; }
#pragma unroll
    for (int ks = 0; ks < 4; ++ks) {
      const u16* wb = w2b + ks * 32 + q * 8;
      short8 fI = *(const short8*)(wb + (size_t)(mt * 16 + col) * HSZ);
      short8 fC = *(const short8*)(wb + (size_t)(256 + mt * 16 + col) * HSZ);
      short8 fO = *(const short8*)(wb + (size_t)(384 + mt * 16 + col) * HSZ);
#pragma unroll
      for (int g = 0; g < NG; ++g) {
        aI[g] = __builtin_amdgcn_mfma_f32_16x16x32_bf16(fI, hf[g][ks], aI[g], 0, 0, 0);
        aC[g] = __builtin_amdgcn_mfma_f32_16x16x32_bf16(fC, hf[g][ks], aC[g], 0, 0, 0);
        aO[g] = __builtin_amdgcn_mfma_f32_16x16x32_bf16(fO, hf[g][ks], aO[g], 0, 0, 0);
      }
    }
    float bI[4], bC[4], bO[4];
#pragma unroll
    for (int r = 0; r < 4; ++r) {
      const int h = mt * 16 + q * 4 + r;
      bI[r] = bs2[h]; bC[r] = bs2[256 + h]; bO[r] = bs2[384 + h];
    }
    const int wcol = ((mt * 2 + (q >> 1)) ^ col) * 8 + (q & 1) * 4;
#pragma unroll
    for (int g = 0; g < NG; ++g) {
      u16 hv[4];
#pragma unroll
      for (int r = 0; r < 4; ++r) {
        float c = gate2(aI[g][r] + bI[r], aC[g][r] + bC[r]);
        hv[r] = f2bf(gate2(aO[g][r] + bO[r], TWOLOG2E * c));
      }
      uint2 pk;
      pk.x = (uint32_t)hv[0] | ((uint32_t)hv[1] << 16);
      pk.y = (uint32_t)hv[2] | ((uint32_t)hv[3] << 16);
      *(uint2*)&hbuf[(g * 16 + col) * HSZ + wcol] = pk;
    }
  }
  asm volatile("s_waitcnt lgkmcnt(0)" ::: "memory");

  // ---- reload fragments: now h2
#pragma unroll
  for (int g = 0; g < NG; ++g)
#pragma unroll
    for (int ks = 0; ks < 4; ++ks)
      hf[g][ks] = *(const short8*)&hbuf[(g * 16 + col) * HSZ + ((ks * 4 + q) ^ col) * 8];

  // ---- attention-MLP energy
  float ep[NG];
#pragma unroll
  for (int g = 0; g < NG; ++g) ep[g] = 0.f;
#pragma unroll
  for (int mt = 0; mt < 4; ++mt) {
    f32x4 acc[NG];
#pragma unroll
    for (int g = 0; g < NG; ++g) acc[g] = z;
#pragma unroll
    for (int ks = 0; ks < 4; ++ks) {
      short8 fA = *(const short8*)(wp1b + (size_t)(mt * 16 + col) * HSZ + ks * 32 + q * 8);
#pragma unroll
      for (int g = 0; g < NG; ++g)
        acc[g] = __builtin_amdgcn_mfma_f32_16x16x32_bf16(fA, hf[g][ks], acc[g], 0, 0, 0);
    }
#pragma unroll
    for (int r = 0; r < 4; ++r) {
      const int hp = mt * 16 + q * 4 + r;
      const float b1 = bp1v[hp];
      const float w2 = Wp2[hp];
#pragma unroll
      for (int g = 0; g < NG; ++g)
        ep[g] += fmaxf(acc[g][r] + b1, 0.f) * w2;
    }
  }
#pragma unroll
  for (int g = 0; g < NG; ++g) {
    ep[g] += __shfl_xor(ep[g], 16);
    ep[g] += __shfl_xor(ep[g], 32);
  }
  const float bp2f = bp2v[0];

  // ---- masked softmax (token l = g*16 + col)
  float e[NG]; bool val[NG];
  float m = -3.0e38f;
#pragma unroll
  for (int g = 0; g < NG; ++g) {
    val[g] = (g * 16 + col) < len;
    e[g] = ep[g] + bp2f;
    m = fmaxf(m, val[g] ? e[g] : -3.0e38f);
  }
  m = fmaxf(m, __shfl_xor(m, 1));
  m = fmaxf(m, __shfl_xor(m, 2));
  m = fmaxf(m, __shfl_xor(m, 4));
  m = fmaxf(m, __shfl_xor(m, 8));
  float wgt[NG], s = 0.f;
#pragma unroll
  for (int g = 0; g < NG; ++g) {
    wgt[g] = val[g] ? __expf(e[g] - m) : 0.f;
    s += wgt[g];
  }
  s += __shfl_xor(s, 1);
  s += __shfl_xor(s, 2);
  s += __shfl_xor(s, 4);
  s += __shfl_xor(s, 8);
  const float inv = __builtin_amdgcn_rcpf(s);
  if (q == 0) {
#pragma unroll
    for (int g = 0; g < NG; ++g) wbuf[g * 16 + col] = wgt[g] * inv;
  }
  asm volatile("s_waitcnt lgkmcnt(0)" ::: "memory");

  // ---- weighted sum: te[h] = sum_l w[l] * h2[l][h]
  // lane covers h = 4*(lane&31)..+3; positions l = 2*i + (lane>>5)
  const int half = lane >> 5;
  const int hb   = (lane & 31) * 4;
  const int rchunk = hb >> 3;
  float a4[4] = {0.f, 0.f, 0.f, 0.f};
#pragma unroll
  for (int g = 0; g < NG; ++g) {
#pragma unroll
    for (int i = 0; i < 8; ++i) {
      const int l = g * 16 + 2 * i + half;
      const float wl = wbuf[l];
      const int sw = ((rchunk ^ (l & 15)) * 8) + (hb & 7);
      const uint2 hv = *(const uint2*)&hbuf[l * HSZ + sw];
      a4[0] += wl * bf2f((u16)(hv.x & 0xffffu));
      a4[1] += wl * bf2f((u16)(hv.x >> 16));
      a4[2] += wl * bf2f((u16)(hv.y & 0xffffu));
      a4[3] += wl * bf2f((u16)(hv.y >> 16));
    }
  }
#pragma unroll
  for (int k = 0; k < 4; ++k) a4[k] += __shfl_xor(a4[k], 32);

  if (half == 0) {
    f32x4 st = {a4[0], a4[1], a4[2], a4[3]};
    *(f32x4*)&partials[(size_t)t * HSZ + hb] = st;
  }
}

// ---------------------------------------------------------------------------
// k_fused: 1 wave per block, TWO traces per block processed sequentially.
// Grid = 2048 blocks -> exactly 8 blocks/CU (LDS cap 9), all resident from
// t=0: no replacement churn, sqrt(2) lower duration variance.
// ---------------------------------------------------------------------------
__global__ __launch_bounds__(64) void k_fused(
    const u16* __restrict__ embb,
    const u16* __restrict__ w1b, const float* __restrict__ bs1,
    const u16* __restrict__ w2b, const float* __restrict__ bs2,
    const u16* __restrict__ wp1b,
    const float* __restrict__ bp1v, const float* __restrict__ Wp2,
    const float* __restrict__ bp2v,
    const int* __restrict__ traces, const int* __restrict__ lengths,
    float* __restrict__ partials)
{
  __shared__ u16 hbuf[TLEN * HSZ];   // 16 KB
  __shared__ float wbuf[TLEN];       // 256 B
#pragma unroll 1
  for (int s = 0; s < 2; ++s) {
    const int t = blockIdx.x * 2 + s;
    const int len = lengths[t];
    const int ngrp = (len + 15) >> 4;
    switch (ngrp) {
      case 1: trace_body<1>(hbuf, wbuf, embb, w1b, bs1, w2b, bs2, wp1b,
                            bp1v, Wp2, bp2v, traces, partials, t, len); break;
      case 2: trace_body<2>(hbuf, wbuf, embb, w1b, bs1, w2b, bs2, wp1b,
                            bp1v, Wp2, bp2v, traces, partials, t, len); break;
      case 3: trace_body<3>(hbuf, wbuf, embb, w1b, bs1, w2b, bs2, wp1b,
                            bp1v, Wp2, bp2v, traces, partials, t, len); break;
      default: trace_body<4>(hbuf, wbuf, embb, w1b, bs1, w2b, bs2, wp1b,
                             bp1v, Wp2, bp2v, traces, partials, t, len); break;
    }
  }
}

// ---------------------------------------------------------------------------
// k_reduce: coalesced. Block j sums rows j*32..j*32+31 (f32x4 row-contiguous
// loads), LDS cross-reduce, 128 atomicAdds/block into fin (zeroed in k_prep).
// ---------------------------------------------------------------------------
__global__ __launch_bounds__(256) void k_reduce(
    const float* __restrict__ partials, float* __restrict__ fin)
{
  __shared__ f32x4 red[256];
  const int tid = threadIdx.x;
  const int c4  = (tid & 31) * 4;
  const int rg  = tid >> 5;
  f32x4 acc = {0.f, 0.f, 0.f, 0.f};
  const int rbase = blockIdx.x * 32;
#pragma unroll
  for (int k = 0; k < 4; ++k) {
    const int row = rbase + rg + 8 * k;
    const f32x4 v = *(const f32x4*)&partials[(size_t)row * HSZ + c4];
    acc[0] += v[0]; acc[1] += v[1]; acc[2] += v[2]; acc[3] += v[3];
  }
  red[tid] = acc;
  __syncthreads();
  if (tid < 32) {
    f32x4 s = red[tid];
#pragma unroll
    for (int m = 1; m < 8; ++m) {
      const f32x4 v = red[tid + 32 * m];
      s[0] += v[0]; s[1] += v[1]; s[2] += v[2]; s[3] += v[3];
    }
    atomicAdd(&fin[c4 + 0], s[0]);
    atomicAdd(&fin[c4 + 1], s[1]);
    atomicAdd(&fin[c4 + 2], s[2]);
    atomicAdd(&fin[c4 + 3], s[3]);
  }
}

// out = final @ W_out.T + b_out   (128x128, one block, FP32)
__global__ __launch_bounds__(128) void k_out(
    const float* __restrict__ fin, const float* __restrict__ W_out,
    const float* __restrict__ b_out, float* __restrict__ out)
{
  const int o = threadIdx.x;
  __shared__ float fs[HSZ];
  fs[o] = fin[o];
  __syncthreads();
  float acc = b_out[o];
  const float* wr = W_out + (size_t)o * HSZ;
#pragma unroll
  for (int h = 0; h < HSZ; ++h) acc += wr[h] * fs[h];
  out[o] = acc;
}

extern "C" void kernel_launch(void* const* d_in, const int* in_sizes, int n_in,
                              void* d_out, int out_size, void* d_ws, size_t ws_size,
                              hipStream_t stream)
{
  const float* emb   = (const float*)d_in[0];
  const float* W_ih1 = (const float*)d_in[1];
  // d_in[2] = W_hh1: unused (h0 = 0)
  const float* b_ih1 = (const float*)d_in[3];
  const float* b_hh1 = (const float*)d_in[4];
  const float* W_ih2 = (const float*)d_in[5];
  // d_in[6] = W_hh2: unused
  const float* b_ih2 = (const float*)d_in[7];
  const float* b_hh2 = (const float*)d_in[8];
  const float* Wp1   = (const float*)d_in[9];
  const float* bp1   = (const float*)d_in[10];
  const float* Wp2   = (const float*)d_in[11];
  const float* bp2   = (const float*)d_in[12];
  const float* W_out = (const float*)d_in[13];
  const float* b_out = (const float*)d_in[14];
  const int* traces  = (const int*)d_in[15];
  const int* lengths = (const int*)d_in[16];

  char* ws = (char*)d_ws;
  u16*   w1b      = (u16*)(ws);                  // 512*64*2   = 65536 B
  u16*   w2b      = (u16*)(ws + 65536);          // 512*128*2  = 131072 B
  u16*   wp1b     = (u16*)(ws + 196608);         // 64*128*2   = 16384 B
  float* bs1      = (float*)(ws + 212992);       // 2048 B
  float* bs2      = (float*)(ws + 215040);       // 2048 B
  float* fin      = (float*)(ws + 217088);       // 512 B
  float* partials = (float*)(ws + 217600);       // 4096*128*4 = 2 MiB
  u16*   embb     = (u16*)(ws + 2314752);        // 10000*64*2 = 1280000 B

  k_prep<<<256, 256, 0, stream>>>(emb, W_ih1, W_ih2, Wp1, b_ih1, b_hh1,
                                  b_ih2, b_hh2, embb, w1b, w2b, wp1b,
                                  bs1, bs2, fin);
  k_fused<<<NBLK / 2, 64, 0, stream>>>(embb, w1b, bs1, w2b, bs2, wp1b,
                                       bp1, Wp2, bp2, traces, lengths, partials);
  k_reduce<<<128, 256, 0, stream>>>(partials, fin);
  k_out<<<1, 128, 0, stream>>>(fin, W_out, b_out, (float*)d_out);
}

// Round 3
// 211.397 us; speedup vs baseline: 1.6625x; 1.1948x over previous
//
#include <hip/hip_runtime.h>
#include <stdint.h>

typedef unsigned short u16;
typedef __attribute__((ext_vector_type(8))) short short8;
typedef __attribute__((ext_vector_type(4))) float f32x4;

#define NTRACE 4096
#define TLEN   64
#define ISZ    64
#define HSZ    128
#define NBLK   NTRACE
#define NBIN   64

#define LOG2E     1.44269504088896f
#define TWOLOG2E  2.88539008177793f

__device__ __forceinline__ float bf2f(u16 u) {
  union { uint32_t i; float f; } v; v.i = ((uint32_t)u) << 16; return v.f;
}
__device__ __forceinline__ u16 f2bf(float f) {
  union { float f; uint32_t i; } v; v.f = f;
  uint32_t r = v.i + 0x7fffu + ((v.i >> 16) & 1u);
  return (u16)(r >> 16);
}
// raw v_exp_f32 (= exp2). Scale factors pre-folded into weights/biases.
__device__ __forceinline__ float fexp2(float x) {
  float r;
  asm("v_exp_f32 %0, %1" : "=v"(r) : "v"(x));
  return r;
}
// tanh(a)*sigmoid(b) given pre-scaled gates:
//   gB = -log2e * b  (sigmoid gate),  gE = 2*log2e * a  (tanh gate)
// = (E-1) / ((E+1)*(1+B)) with E=exp2(gE), B=exp2(gB)
__device__ __forceinline__ float gate2(float gB, float gE) {
  float E = fexp2(gE);
  float B = fexp2(gB);
  return (E - 1.0f) * __builtin_amdgcn_rcpf((E + 1.0f) * (1.0f + B));
}

// ---------------------------------------------------------------------------
// k_prep: f32->bf16 weight conversion with exp2 scale folding, bias sums,
// emb -> bf16, bins zero.
// Gate rows (torch order i,f,g,o): [0,256)+[384,512) sigmoid * -log2e ;
// [256,384) tanh * 2*log2e.
// ---------------------------------------------------------------------------
__global__ __launch_bounds__(256) void k_prep(
    const float* __restrict__ emb,
    const float* __restrict__ W1, const float* __restrict__ W2,
    const float* __restrict__ Wp1,
    const float* __restrict__ b_ih1, const float* __restrict__ b_hh1,
    const float* __restrict__ b_ih2, const float* __restrict__ b_hh2,
    u16* __restrict__ embb,
    u16* __restrict__ w1b, u16* __restrict__ w2b, u16* __restrict__ wp1b,
    float* __restrict__ bs1, float* __restrict__ bs2,
    float* __restrict__ bins)
{
  const int i = blockIdx.x * 256 + threadIdx.x;   // 65536 threads
  if (i < 512 * 64) {
    const int r = i >> 6;
    const float s = (r >= 256 && r < 384) ? TWOLOG2E : -LOG2E;
    w1b[i] = f2bf(W1[i] * s);
  }
  if (i < 512 * 128) {
    const int r = i >> 7;
    const float s = (r >= 256 && r < 384) ? TWOLOG2E : -LOG2E;
    w2b[i] = f2bf(W2[i] * s);
  }
  if (i < 64 * 128) wp1b[i] = f2bf(Wp1[i]);
  if (i < 512) {
    const float s = (i >= 256 && i < 384) ? TWOLOG2E : -LOG2E;
    bs1[i] = (b_ih1[i] + b_hh1[i]) * s;
    bs2[i] = (b_ih2[i] + b_hh2[i]) * s;
  }
  if (i < NBIN * HSZ) bins[i] = 0.f;
  for (int j = i; j < 10000 * 64; j += 256 * 256) embb[j] = f2bf(emb[j]);
}

// ---------------------------------------------------------------------------
// trace_body<NG>: one wave, one trace, NG = ceil(len/16) active token groups.
// Branch-free per instantiation; weight loads amortized over NG groups.
// hbuf XOR-chunk swizzle: (token,h) -> column ((h>>3)^(token&15))*8 + (h&7).
// All hbuf accesses via __builtin_memcpy (alias-conservative): no asm
// barriers needed -> compiler free to hoist global weight loads across the
// gate-VALU phases.
// ---------------------------------------------------------------------------
template<int NG>
__device__ __forceinline__ void trace_body(
    u16* __restrict__ hbuf,            // [TLEN][HSZ] flat, wave-private
    float* __restrict__ wbuf,          // [TLEN] softmax weights
    const u16* __restrict__ embb,
    const u16* __restrict__ w1b, const float* __restrict__ bs1,
    const u16* __restrict__ w2b, const float* __restrict__ bs2,
    const u16* __restrict__ wp1b,
    const float* __restrict__ bp1v, const float* __restrict__ Wp2,
    const float* __restrict__ bp2v,
    const int* __restrict__ traces,
    float* __restrict__ bin, int t, int len)
{
  const int lane = threadIdx.x & 63;
  const int col  = lane & 15;
  const int q    = lane >> 4;
  const f32x4 z = {0.f, 0.f, 0.f, 0.f};

  // ---- x fragments (bf16 emb, B-operand of lstm1)
  short8 xf[NG][2];
#pragma unroll
  for (int g = 0; g < NG; ++g) {
    const int tok = traces[t * TLEN + g * 16 + col];
    const u16* xr = embb + (size_t)tok * ISZ + q * 8;
    xf[g][0] = *(const short8*)(xr);
    xf[g][1] = *(const short8*)(xr + 32);
  }

  // ---- LSTM layer 1 (K=64); gate rows i@0, g@256, o@384
#pragma unroll
  for (int mt = 0; mt < 8; ++mt) {
    f32x4 aI[NG], aC[NG], aO[NG];
#pragma unroll
    for (int g = 0; g < NG; ++g) { aI[g] = z; aC[g] = z; aO[g] = z; }
#pragma unroll
    for (int ks = 0; ks < 2; ++ks) {
      const u16* wb = w1b + ks * 32 + q * 8;
      short8 fI = *(const short8*)(wb + (size_t)(mt * 16 + col) * ISZ);
      short8 fC = *(const short8*)(wb + (size_t)(256 + mt * 16 + col) * ISZ);
      short8 fO = *(const short8*)(wb + (size_t)(384 + mt * 16 + col) * ISZ);
#pragma unroll
      for (int g = 0; g < NG; ++g) {
        aI[g] = __builtin_amdgcn_mfma_f32_16x16x32_bf16(fI, xf[g][ks], aI[g], 0, 0, 0);
        aC[g] = __builtin_amdgcn_mfma_f32_16x16x32_bf16(fC, xf[g][ks], aC[g], 0, 0, 0);
        aO[g] = __builtin_amdgcn_mfma_f32_16x16x32_bf16(fO, xf[g][ks], aO[g], 0, 0, 0);
      }
    }
    float bI[4], bC[4], bO[4];
#pragma unroll
    for (int r = 0; r < 4; ++r) {
      const int h = mt * 16 + q * 4 + r;
      bI[r] = bs1[h]; bC[r] = bs1[256 + h]; bO[r] = bs1[384 + h];
    }
    const int wcol = ((mt * 2 + (q >> 1)) ^ col) * 8 + (q & 1) * 4;
#pragma unroll
    for (int g = 0; g < NG; ++g) {
      u16 hv[4];
#pragma unroll
      for (int r = 0; r < 4; ++r) {
        float c = gate2(aI[g][r] + bI[r], aC[g][r] + bC[r]);
        hv[r] = f2bf(gate2(aO[g][r] + bO[r], TWOLOG2E * c));
      }
      uint32_t pk[2];
      pk[0] = (uint32_t)hv[0] | ((uint32_t)hv[1] << 16);
      pk[1] = (uint32_t)hv[2] | ((uint32_t)hv[3] << 16);
      __builtin_memcpy(&hbuf[(g * 16 + col) * HSZ + wcol], pk, 8);
    }
  }

  // ---- h1 fragments (B-operand of lstm2), swizzled reads
  short8 hf[NG][4];
#pragma unroll
  for (int g = 0; g < NG; ++g)
#pragma unroll
    for (int ks = 0; ks < 4; ++ks)
      __builtin_memcpy(&hf[g][ks],
                       &hbuf[(g * 16 + col) * HSZ + ((ks * 4 + q) ^ col) * 8], 16);

  // ---- LSTM layer 2 (K=128)
#pragma unroll
  for (int mt = 0; mt < 8; ++mt) {
    f32x4 aI[NG], aC[NG], aO[NG];
#pragma unroll
    for (int g = 0; g < NG; ++g) { aI[g] = z; aC[g] = z; aO[g] = z; }
#pragma unroll
    for (int ks = 0; ks < 4; ++ks) {
      const u16* wb = w2b + ks * 32 + q * 8;
      short8 fI = *(const short8*)(wb + (size_t)(mt * 16 + col) * HSZ);
      short8 fC = *(const short8*)(wb + (size_t)(256 + mt * 16 + col) * HSZ);
      short8 fO = *(const short8*)(wb + (size_t)(384 + mt * 16 + col) * HSZ);
#pragma unroll
      for (int g = 0; g < NG; ++g) {
        aI[g] = __builtin_amdgcn_mfma_f32_16x16x32_bf16(fI, hf[g][ks], aI[g], 0, 0, 0);
        aC[g] = __builtin_amdgcn_mfma_f32_16x16x32_bf16(fC, hf[g][ks], aC[g], 0, 0, 0);
        aO[g] = __builtin_amdgcn_mfma_f32_16x16x32_bf16(fO, hf[g][ks], aO[g], 0, 0, 0);
      }
    }
    float bI[4], bC[4], bO[4];
#pragma unroll
    for (int r = 0; r < 4; ++r) {
      const int h = mt * 16 + q * 4 + r;
      bI[r] = bs2[h]; bC[r] = bs2[256 + h]; bO[r] = bs2[384 + h];
    }
    const int wcol = ((mt * 2 + (q >> 1)) ^ col) * 8 + (q & 1) * 4;
#pragma unroll
    for (int g = 0; g < NG; ++g) {
      u16 hv[4];
#pragma unroll
      for (int r = 0; r < 4; ++r) {
        float c = gate2(aI[g][r] + bI[r], aC[g][r] + bC[r]);
        hv[r] = f2bf(gate2(aO[g][r] + bO[r], TWOLOG2E * c));
      }
      uint32_t pk[2];
      pk[0] = (uint32_t)hv[0] | ((uint32_t)hv[1] << 16);
      pk[1] = (uint32_t)hv[2] | ((uint32_t)hv[3] << 16);
      __builtin_memcpy(&hbuf[(g * 16 + col) * HSZ + wcol], pk, 8);
    }
  }

  // ---- reload fragments: now h2
#pragma unroll
  for (int g = 0; g < NG; ++g)
#pragma unroll
    for (int ks = 0; ks < 4; ++ks)
      __builtin_memcpy(&hf[g][ks],
                       &hbuf[(g * 16 + col) * HSZ + ((ks * 4 + q) ^ col) * 8], 16);

  // ---- attention-MLP energy
  float ep[NG];
#pragma unroll
  for (int g = 0; g < NG; ++g) ep[g] = 0.f;
#pragma unroll
  for (int mt = 0; mt < 4; ++mt) {
    f32x4 acc[NG];
#pragma unroll
    for (int g = 0; g < NG; ++g) acc[g] = z;
#pragma unroll
    for (int ks = 0; ks < 4; ++ks) {
      short8 fA = *(const short8*)(wp1b + (size_t)(mt * 16 + col) * HSZ + ks * 32 + q * 8);
#pragma unroll
      for (int g = 0; g < NG; ++g)
        acc[g] = __builtin_amdgcn_mfma_f32_16x16x32_bf16(fA, hf[g][ks], acc[g], 0, 0, 0);
    }
#pragma unroll
    for (int r = 0; r < 4; ++r) {
      const int hp = mt * 16 + q * 4 + r;
      const float b1 = bp1v[hp];
      const float w2 = Wp2[hp];
#pragma unroll
      for (int g = 0; g < NG; ++g)
        ep[g] += fmaxf(acc[g][r] + b1, 0.f) * w2;
    }
  }
#pragma unroll
  for (int g = 0; g < NG; ++g) {
    ep[g] += __shfl_xor(ep[g], 16);
    ep[g] += __shfl_xor(ep[g], 32);
  }
  const float bp2f = bp2v[0];

  // ---- masked softmax (token l = g*16 + col)
  float e[NG]; bool val[NG];
  float m = -3.0e38f;
#pragma unroll
  for (int g = 0; g < NG; ++g) {
    val[g] = (g * 16 + col) < len;
    e[g] = ep[g] + bp2f;
    m = fmaxf(m, val[g] ? e[g] : -3.0e38f);
  }
  m = fmaxf(m, __shfl_xor(m, 1));
  m = fmaxf(m, __shfl_xor(m, 2));
  m = fmaxf(m, __shfl_xor(m, 4));
  m = fmaxf(m, __shfl_xor(m, 8));
  float wgt[NG], s = 0.f;
#pragma unroll
  for (int g = 0; g < NG; ++g) {
    wgt[g] = val[g] ? __expf(e[g] - m) : 0.f;
    s += wgt[g];
  }
  s += __shfl_xor(s, 1);
  s += __shfl_xor(s, 2);
  s += __shfl_xor(s, 4);
  s += __shfl_xor(s, 8);
  const float inv = __builtin_amdgcn_rcpf(s);
  if (q == 0) {
#pragma unroll
    for (int g = 0; g < NG; ++g) wbuf[g * 16 + col] = wgt[g] * inv;
  }

  // ---- weighted sum: te[h] = sum_l w[l] * h2[l][h]
  // lane covers h = 4*(lane&31)..+3; positions l = 2*i + (lane>>5)
  const int half = lane >> 5;
  const int hb   = (lane & 31) * 4;
  const int rchunk = hb >> 3;
  float a4[4] = {0.f, 0.f, 0.f, 0.f};
#pragma unroll
  for (int g = 0; g < NG; ++g) {
#pragma unroll
    for (int i = 0; i < 8; ++i) {
      const int l = g * 16 + 2 * i + half;
      const float wl = wbuf[l];
      const int sw = ((rchunk ^ (l & 15)) * 8) + (hb & 7);
      uint32_t hv[2];
      __builtin_memcpy(hv, &hbuf[l * HSZ + sw], 8);
      a4[0] += wl * bf2f((u16)(hv[0] & 0xffffu));
      a4[1] += wl * bf2f((u16)(hv[0] >> 16));
      a4[2] += wl * bf2f((u16)(hv[1] & 0xffffu));
      a4[3] += wl * bf2f((u16)(hv[1] >> 16));
    }
  }
#pragma unroll
  for (int k = 0; k < 4; ++k) a4[k] += __shfl_xor(a4[k], 32);

  // ---- fire-and-forget atomic accumulate into this trace's bin
  if (half == 0) {
#pragma unroll
    for (int k = 0; k < 4; ++k) atomicAdd(&bin[hb + k], a4[k]);
  }
}

// ---------------------------------------------------------------------------
// k_fused: 1 wave per block, 1 trace per block; uniform template dispatch
// (tail-position switch keeps regalloc per-path; R2's loop variant hit 256
// VGPR). launch_bounds(64,3) guards VGPR <= ~168 without forcing spills.
// ---------------------------------------------------------------------------
__global__ __launch_bounds__(64, 3) void k_fused(
    const u16* __restrict__ embb,
    const u16* __restrict__ w1b, const float* __restrict__ bs1,
    const u16* __restrict__ w2b, const float* __restrict__ bs2,
    const u16* __restrict__ wp1b,
    const float* __restrict__ bp1v, const float* __restrict__ Wp2,
    const float* __restrict__ bp2v,
    const int* __restrict__ traces, const int* __restrict__ lengths,
    float* __restrict__ bins)
{
  __shared__ __align__(16) u16 hbuf[TLEN * HSZ];   // 16 KB
  __shared__ float wbuf[TLEN];                     // 256 B
  const int t = blockIdx.x;
  const int len = lengths[t];
  const int ngrp = (len + 15) >> 4;
  float* bin = bins + (size_t)(t & (NBIN - 1)) * HSZ;
  switch (ngrp) {
    case 1: trace_body<1>(hbuf, wbuf, embb, w1b, bs1, w2b, bs2, wp1b,
                          bp1v, Wp2, bp2v, traces, bin, t, len); break;
    case 2: trace_body<2>(hbuf, wbuf, embb, w1b, bs1, w2b, bs2, wp1b,
                          bp1v, Wp2, bp2v, traces, bin, t, len); break;
    case 3: trace_body<3>(hbuf, wbuf, embb, w1b, bs1, w2b, bs2, wp1b,
                          bp1v, Wp2, bp2v, traces, bin, t, len); break;
    default: trace_body<4>(hbuf, wbuf, embb, w1b, bs1, w2b, bs2, wp1b,
                           bp1v, Wp2, bp2v, traces, bin, t, len); break;
  }
}

// ---------------------------------------------------------------------------
// k_out: single block. Reduce 64 bins -> fin (coalesced), then 128x128
// matvec: out = fin @ W_out.T + b_out.
// ---------------------------------------------------------------------------
__global__ __launch_bounds__(128) void k_out(
    const float* __restrict__ bins, const float* __restrict__ W_out,
    const float* __restrict__ b_out, float* __restrict__ out)
{
  const int o = threadIdx.x;      // 0..127
  __shared__ float fs[HSZ];
  float s = 0.f;
#pragma unroll 4
  for (int b = 0; b < NBIN; ++b) s += bins[b * HSZ + o];
  fs[o] = s;
  __syncthreads();
  float acc = b_out[o];
  const float* wr = W_out + (size_t)o * HSZ;
#pragma unroll
  for (int h = 0; h < HSZ; ++h) acc += wr[h] * fs[h];
  out[o] = acc;
}

extern "C" void kernel_launch(void* const* d_in, const int* in_sizes, int n_in,
                              void* d_out, int out_size, void* d_ws, size_t ws_size,
                              hipStream_t stream)
{
  const float* emb   = (const float*)d_in[0];
  const float* W_ih1 = (const float*)d_in[1];
  // d_in[2] = W_hh1: unused (h0 = 0)
  const float* b_ih1 = (const float*)d_in[3];
  const float* b_hh1 = (const float*)d_in[4];
  const float* W_ih2 = (const float*)d_in[5];
  // d_in[6] = W_hh2: unused
  const float* b_ih2 = (const float*)d_in[7];
  const float* b_hh2 = (const float*)d_in[8];
  const float* Wp1   = (const float*)d_in[9];
  const float* bp1   = (const float*)d_in[10];
  const float* Wp2   = (const float*)d_in[11];
  const float* bp2   = (const float*)d_in[12];
  const float* W_out = (const float*)d_in[13];
  const float* b_out = (const float*)d_in[14];
  const int* traces  = (const int*)d_in[15];
  const int* lengths = (const int*)d_in[16];

  char* ws = (char*)d_ws;
  u16*   w1b  = (u16*)(ws);                  // 512*64*2   = 65536 B
  u16*   w2b  = (u16*)(ws + 65536);          // 512*128*2  = 131072 B
  u16*   wp1b = (u16*)(ws + 196608);         // 64*128*2   = 16384 B
  float* bs1  = (float*)(ws + 212992);       // 2048 B
  float* bs2  = (float*)(ws + 215040);       // 2048 B
  float* bins = (float*)(ws + 217088);       // 64*128*4   = 32768 B
  u16*   embb = (u16*)(ws + 249856);         // 10000*64*2 = 1280000 B

  k_prep<<<256, 256, 0, stream>>>(emb, W_ih1, W_ih2, Wp1, b_ih1, b_hh1,
                                  b_ih2, b_hh2, embb, w1b, w2b, wp1b,
                                  bs1, bs2, bins);
  k_fused<<<NBLK, 64, 0, stream>>>(embb, w1b, bs1, w2b, bs2, wp1b,
                                   bp1, Wp2, bp2, traces, lengths, bins);
  k_out<<<1, 128, 0, stream>>>(bins, W_out, b_out, (float*)d_out);
}

// Round 6
// 205.155 us; speedup vs baseline: 1.7130x; 1.0304x over previous
//
#include <hip/hip_runtime.h>
#include <stdint.h>

typedef unsigned short u16;
typedef __attribute__((ext_vector_type(8))) short short8;
typedef __attribute__((ext_vector_type(4))) float f32x4;

#define NTRACE 4096
#define TLEN   64
#define ISZ    64
#define HSZ    128
#define NBIN   64

#define LOG2E     1.44269504088896f
#define TWOLOG2E  2.88539008177793f

__device__ __forceinline__ float bf2f(u16 u) {
  union { uint32_t i; float f; } v; v.i = ((uint32_t)u) << 16; return v.f;
}
__device__ __forceinline__ u16 f2bf(float f) {
  union { float f; uint32_t i; } v; v.f = f;
  uint32_t r = v.i + 0x7fffu + ((v.i >> 16) & 1u);
  return (u16)(r >> 16);
}
__device__ __forceinline__ float fexp2(float x) {
  float r;
  asm("v_exp_f32 %0, %1" : "=v"(r) : "v"(x));
  return r;
}
// tanh(a)*sigmoid(b) with pre-scaled gates: gB=-log2e*b, gE=2log2e*a
__device__ __forceinline__ float gate2(float gB, float gE) {
  float E = fexp2(gE);
  float B = fexp2(gB);
  return (E - 1.0f) * __builtin_amdgcn_rcpf((E + 1.0f) * (1.0f + B));
}
__device__ __forceinline__ short8 mk8(uint32_t a, uint32_t b, uint32_t c, uint32_t d) {
  union { short8 s; uint32_t u[4]; } z;
  z.u[0] = a; z.u[1] = b; z.u[2] = c; z.u[3] = d; return z.s;
}
// Weight-row permutation: buffer tile-row (mt,u) holds true hidden index
// pi = (mt&3)*32 + (u>>2)*8 + (mt>>2)*4 + (u&3), so MFMA C-layout output
// (lane q,col; tile mt; reg r) renames directly into the next layer's
// B-fragment: element j of frag ks = tile ks+4*(j>>2), reg j&3
// => true hidden ks*32+q*8+j.
__device__ __forceinline__ int perm128(int rr) {
  return ((rr >> 4) & 3) * 32 + ((rr >> 2) & 3) * 8 + ((rr >> 6) & 1) * 4 + (rr & 3);
}

// ---------------------------------------------------------------------------
// k_prep: bf16 weight conversion with exp2 scale folding AND pi row
// permutation (W1, W2, biases). Wp1 stays linear (h2 fragment is linear-k).
// Also: emb->bf16, bins zero.
// ---------------------------------------------------------------------------
__global__ __launch_bounds__(256) void k_prep(
    const float* __restrict__ emb,
    const float* __restrict__ W1, const float* __restrict__ W2,
    const float* __restrict__ Wp1,
    const float* __restrict__ b_ih1, const float* __restrict__ b_hh1,
    const float* __restrict__ b_ih2, const float* __restrict__ b_hh2,
    u16* __restrict__ embb,
    u16* __restrict__ w1b, u16* __restrict__ w2b, u16* __restrict__ wp1b,
    float* __restrict__ bs1, float* __restrict__ bs2,
    float* __restrict__ bins)
{
  const int i = blockIdx.x * 256 + threadIdx.x;   // 65536 threads
  if (i < 512 * 64) {
    const int row = i >> 6, G = row >> 7, rr = row & 127;
    const float s = (G == 2) ? TWOLOG2E : -LOG2E;
    w1b[i] = f2bf(W1[(G * 128 + perm128(rr)) * ISZ + (i & 63)] * s);
  }
  if (i < 512 * 128) {
    const int row = i >> 7, G = row >> 7, rr = row & 127;
    const float s = (G == 2) ? TWOLOG2E : -LOG2E;
    w2b[i] = f2bf(W2[(G * 128 + perm128(rr)) * HSZ + (i & 127)] * s);
  }
  if (i < 64 * 128) wp1b[i] = f2bf(Wp1[i]);
  if (i < 512) {
    const int G = i >> 7, rr = i & 127;
    const float s = (G == 2) ? TWOLOG2E : -LOG2E;
    const int src = G * 128 + perm128(rr);
    bs1[i] = (b_ih1[src] + b_hh1[src]) * s;
    bs2[i] = (b_ih2[src] + b_hh2[src]) * s;
  }
  if (i < NBIN * HSZ) bins[i] = 0.f;
  for (int j = i; j < 10000 * 64; j += 256 * 256) embb[j] = f2bf(emb[j]);
}

// ---------------------------------------------------------------------------
// trace_body<NG>: R3-verified skeleton; ONLY change = h1 transpose replaced
// by pi-permutation register rename. h2 still goes to LDS (at TRUE hidden
// positions) for the verified weighted-sum path.
// ---------------------------------------------------------------------------
template<int NG>
__device__ __forceinline__ void trace_body(
    u16* __restrict__ hbuf,            // [TLEN][HSZ] flat
    float* __restrict__ wbuf,          // [TLEN] softmax weights
    const u16* __restrict__ embb,
    const u16* __restrict__ w1b, const float* __restrict__ bs1,
    const u16* __restrict__ w2b, const float* __restrict__ bs2,
    const u16* __restrict__ wp1b,
    const float* __restrict__ bp1v, const float* __restrict__ Wp2,
    const float* __restrict__ bp2v,
    const int* __restrict__ traces,
    float* __restrict__ bin, int t, int len)
{
  const int lane = threadIdx.x & 63;
  const int col  = lane & 15;
  const int q    = lane >> 4;
  const f32x4 z = {0.f, 0.f, 0.f, 0.f};

  // ---- x fragments (bf16 emb, B-operand of lstm1)
  short8 xf[NG][2];
#pragma unroll
  for (int g = 0; g < NG; ++g) {
    const int tok = traces[t * TLEN + g * 16 + col];
    const u16* xr = embb + (size_t)tok * ISZ + q * 8;
    xf[g][0] = *(const short8*)(xr);
    xf[g][1] = *(const short8*)(xr + 32);
  }

  // ---- LSTM layer 1 (K=64); gate rows i@0, g@256, o@384 (pi-permuted rows)
  uint32_t pk[NG][8][2];
#pragma unroll
  for (int mt = 0; mt < 8; ++mt) {
    f32x4 aI[NG], aC[NG], aO[NG];
#pragma unroll
    for (int g = 0; g < NG; ++g) { aI[g] = z; aC[g] = z; aO[g] = z; }
#pragma unroll
    for (int ks = 0; ks < 2; ++ks) {
      const u16* wb = w1b + ks * 32 + q * 8;
      short8 fI = *(const short8*)(wb + (size_t)(mt * 16 + col) * ISZ);
      short8 fC = *(const short8*)(wb + (size_t)(256 + mt * 16 + col) * ISZ);
      short8 fO = *(const short8*)(wb + (size_t)(384 + mt * 16 + col) * ISZ);
#pragma unroll
      for (int g = 0; g < NG; ++g) {
        aI[g] = __builtin_amdgcn_mfma_f32_16x16x32_bf16(fI, xf[g][ks], aI[g], 0, 0, 0);
        aC[g] = __builtin_amdgcn_mfma_f32_16x16x32_bf16(fC, xf[g][ks], aC[g], 0, 0, 0);
        aO[g] = __builtin_amdgcn_mfma_f32_16x16x32_bf16(fO, xf[g][ks], aO[g], 0, 0, 0);
      }
    }
    float bI[4], bC[4], bO[4];
#pragma unroll
    for (int r = 0; r < 4; ++r) {
      const int h = mt * 16 + q * 4 + r;   // buffer row (permuted bs1 matches)
      bI[r] = bs1[h]; bC[r] = bs1[256 + h]; bO[r] = bs1[384 + h];
    }
#pragma unroll
    for (int g = 0; g < NG; ++g) {
      u16 hv[4];
#pragma unroll
      for (int r = 0; r < 4; ++r) {
        float c = gate2(aI[g][r] + bI[r], aC[g][r] + bC[r]);
        hv[r] = f2bf(gate2(aO[g][r] + bO[r], TWOLOG2E * c));
      }
      pk[g][mt][0] = (uint32_t)hv[0] | ((uint32_t)hv[1] << 16);
      pk[g][mt][1] = (uint32_t)hv[2] | ((uint32_t)hv[3] << 16);
    }
  }

  // ---- h1 fragments: pure register rename (pi permutation)
  short8 hf[NG][4];
#pragma unroll
  for (int g = 0; g < NG; ++g)
#pragma unroll
    for (int ks = 0; ks < 4; ++ks)
      hf[g][ks] = mk8(pk[g][ks][0], pk[g][ks][1], pk[g][ks + 4][0], pk[g][ks + 4][1]);

  // ---- LSTM layer 2 (K=128); h2 stored to LDS at TRUE hidden positions
  uint32_t pk2[NG][8][2];
#pragma unroll
  for (int mt = 0; mt < 8; ++mt) {
    f32x4 aI[NG], aC[NG], aO[NG];
#pragma unroll
    for (int g = 0; g < NG; ++g) { aI[g] = z; aC[g] = z; aO[g] = z; }
#pragma unroll
    for (int ks = 0; ks < 4; ++ks) {
      const u16* wb = w2b + ks * 32 + q * 8;
      short8 fI = *(const short8*)(wb + (size_t)(mt * 16 + col) * HSZ);
      short8 fC = *(const short8*)(wb + (size_t)(256 + mt * 16 + col) * HSZ);
      short8 fO = *(const short8*)(wb + (size_t)(384 + mt * 16 + col) * HSZ);
#pragma unroll
      for (int g = 0; g < NG; ++g) {
        aI[g] = __builtin_amdgcn_mfma_f32_16x16x32_bf16(fI, hf[g][ks], aI[g], 0, 0, 0);
        aC[g] = __builtin_amdgcn_mfma_f32_16x16x32_bf16(fC, hf[g][ks], aC[g], 0, 0, 0);
        aO[g] = __builtin_amdgcn_mfma_f32_16x16x32_bf16(fO, hf[g][ks], aO[g], 0, 0, 0);
      }
    }
    float bI[4], bC[4], bO[4];
#pragma unroll
    for (int r = 0; r < 4; ++r) {
      const int h = mt * 16 + q * 4 + r;
      bI[r] = bs2[h]; bC[r] = bs2[256 + h]; bO[r] = bs2[384 + h];
    }
    // true hidden base of this (mt,q) quad: (mt&3)*32 + q*8 + (mt>>2)*4
    // -> chunk (mt&3)*4+q, in-chunk offset (mt>>2)*4, R0 XOR-chunk swizzle.
    const int wcol = ((((mt & 3) * 4 + q) ^ col) * 8) + (mt >> 2) * 4;
#pragma unroll
    for (int g = 0; g < NG; ++g) {
      u16 hv[4];
#pragma unroll
      for (int r = 0; r < 4; ++r) {
        float c = gate2(aI[g][r] + bI[r], aC[g][r] + bC[r]);
        hv[r] = f2bf(gate2(aO[g][r] + bO[r], TWOLOG2E * c));
      }
      uint32_t pkk[2];
      pkk[0] = (uint32_t)hv[0] | ((uint32_t)hv[1] << 16);
      pkk[1] = (uint32_t)hv[2] | ((uint32_t)hv[3] << 16);
      pk2[g][mt][0] = pkk[0];
      pk2[g][mt][1] = pkk[1];
      __builtin_memcpy(&hbuf[(g * 16 + col) * HSZ + wcol], pkk, 8);
    }
  }

  // ---- h2 fragments (linear-k) via rename for the MLP
  short8 hf2[NG][4];
#pragma unroll
  for (int g = 0; g < NG; ++g)
#pragma unroll
    for (int ks = 0; ks < 4; ++ks)
      hf2[g][ks] = mk8(pk2[g][ks][0], pk2[g][ks][1], pk2[g][ks + 4][0], pk2[g][ks + 4][1]);

  // ---- attention-MLP energy (R3 structure, frags from rename)
  float ep[NG];
#pragma unroll
  for (int g = 0; g < NG; ++g) ep[g] = 0.f;
#pragma unroll
  for (int mt = 0; mt < 4; ++mt) {
    f32x4 acc[NG];
#pragma unroll
    for (int g = 0; g < NG; ++g) acc[g] = z;
#pragma unroll
    for (int ks = 0; ks < 4; ++ks) {
      short8 fA = *(const short8*)(wp1b + (size_t)(mt * 16 + col) * HSZ + ks * 32 + q * 8);
#pragma unroll
      for (int g = 0; g < NG; ++g)
        acc[g] = __builtin_amdgcn_mfma_f32_16x16x32_bf16(fA, hf2[g][ks], acc[g], 0, 0, 0);
    }
#pragma unroll
    for (int r = 0; r < 4; ++r) {
      const int hp = mt * 16 + q * 4 + r;
      const float b1 = bp1v[hp];
      const float w2 = Wp2[hp];
#pragma unroll
      for (int g = 0; g < NG; ++g)
        ep[g] += fmaxf(acc[g][r] + b1, 0.f) * w2;
    }
  }
#pragma unroll
  for (int g = 0; g < NG; ++g) {
    ep[g] += __shfl_xor(ep[g], 16);
    ep[g] += __shfl_xor(ep[g], 32);
  }
  const float bp2f = bp2v[0];

  // ---- masked softmax (R3 verbatim; token l = g*16 + col)
  float e[NG]; bool val[NG];
  float m = -3.0e38f;
#pragma unroll
  for (int g = 0; g < NG; ++g) {
    val[g] = (g * 16 + col) < len;
    e[g] = ep[g] + bp2f;
    m = fmaxf(m, val[g] ? e[g] : -3.0e38f);
  }
  m = fmaxf(m, __shfl_xor(m, 1));
  m = fmaxf(m, __shfl_xor(m, 2));
  m = fmaxf(m, __shfl_xor(m, 4));
  m = fmaxf(m, __shfl_xor(m, 8));
  float wgt[NG], s = 0.f;
#pragma unroll
  for (int g = 0; g < NG; ++g) {
    wgt[g] = val[g] ? __expf(e[g] - m) : 0.f;
    s += wgt[g];
  }
  s += __shfl_xor(s, 1);
  s += __shfl_xor(s, 2);
  s += __shfl_xor(s, 4);
  s += __shfl_xor(s, 8);
  const float inv = __builtin_amdgcn_rcpf(s);
  if (q == 0) {
#pragma unroll
    for (int g = 0; g < NG; ++g) wbuf[g * 16 + col] = wgt[g] * inv;
  }

  // ---- weighted sum from LDS (R3 verbatim; hbuf holds TRUE hidden layout)
  const int half = lane >> 5;
  const int hb   = (lane & 31) * 4;
  const int rchunk = hb >> 3;
  float a4[4] = {0.f, 0.f, 0.f, 0.f};
#pragma unroll
  for (int g = 0; g < NG; ++g) {
#pragma unroll
    for (int i = 0; i < 8; ++i) {
      const int l = g * 16 + 2 * i + half;
      const float wl = wbuf[l];
      const int sw = ((rchunk ^ (l & 15)) * 8) + (hb & 7);
      uint32_t hv[2];
      __builtin_memcpy(hv, &hbuf[l * HSZ + sw], 8);
      a4[0] += wl * bf2f((u16)(hv[0] & 0xffffu));
      a4[1] += wl * bf2f((u16)(hv[0] >> 16));
      a4[2] += wl * bf2f((u16)(hv[1] & 0xffffu));
      a4[3] += wl * bf2f((u16)(hv[1] >> 16));
    }
  }
#pragma unroll
  for (int k = 0; k < 4; ++k) a4[k] += __shfl_xor(a4[k], 32);

  if (half == 0) {
#pragma unroll
    for (int k = 0; k < 4; ++k) atomicAdd(&bin[hb + k], a4[k]);
  }
}

// ---------------------------------------------------------------------------
// k_fused: 1 wave per block, 1 trace per block (blockIdx = t, no order[]).
// ---------------------------------------------------------------------------
__global__ __launch_bounds__(64, 2) void k_fused(
    const u16* __restrict__ embb,
    const u16* __restrict__ w1b, const float* __restrict__ bs1,
    const u16* __restrict__ w2b, const float* __restrict__ bs2,
    const u16* __restrict__ wp1b,
    const float* __restrict__ bp1v, const float* __restrict__ Wp2,
    const float* __restrict__ bp2v,
    const int* __restrict__ traces, const int* __restrict__ lengths,
    float* __restrict__ bins)
{
  __shared__ __align__(16) u16 hbuf[TLEN * HSZ];   // 16 KB (h2 only)
  __shared__ float wbuf[TLEN];                     // 256 B
  const int t = blockIdx.x;
  const int len = lengths[t];
  const int ngrp = (len + 15) >> 4;
  float* bin = bins + (size_t)(t & (NBIN - 1)) * HSZ;
  switch (ngrp) {
    case 1: trace_body<1>(hbuf, wbuf, embb, w1b, bs1, w2b, bs2, wp1b,
                          bp1v, Wp2, bp2v, traces, bin, t, len); break;
    case 2: trace_body<2>(hbuf, wbuf, embb, w1b, bs1, w2b, bs2, wp1b,
                          bp1v, Wp2, bp2v, traces, bin, t, len); break;
    case 3: trace_body<3>(hbuf, wbuf, embb, w1b, bs1, w2b, bs2, wp1b,
                          bp1v, Wp2, bp2v, traces, bin, t, len); break;
    default: trace_body<4>(hbuf, wbuf, embb, w1b, bs1, w2b, bs2, wp1b,
                           bp1v, Wp2, bp2v, traces, bin, t, len); break;
  }
}

// ---------------------------------------------------------------------------
// k_out: single block. Reduce 64 bins -> fin, then 128x128 matvec. (R3.)
// ---------------------------------------------------------------------------
__global__ __launch_bounds__(128) void k_out(
    const float* __restrict__ bins, const float* __restrict__ W_out,
    const float* __restrict__ b_out, float* __restrict__ out)
{
  const int o = threadIdx.x;      // 0..127
  __shared__ float fs[HSZ];
  float s = 0.f;
#pragma unroll 4
  for (int b = 0; b < NBIN; ++b) s += bins[b * HSZ + o];
  fs[o] = s;
  __syncthreads();
  float acc = b_out[o];
  const float* wr = W_out + (size_t)o * HSZ;
#pragma unroll
  for (int h = 0; h < HSZ; ++h) acc += wr[h] * fs[h];
  out[o] = acc;
}

extern "C" void kernel_launch(void* const* d_in, const int* in_sizes, int n_in,
                              void* d_out, int out_size, void* d_ws, size_t ws_size,
                              hipStream_t stream)
{
  const float* emb   = (const float*)d_in[0];
  const float* W_ih1 = (const float*)d_in[1];
  // d_in[2] = W_hh1: unused (h0 = 0)
  const float* b_ih1 = (const float*)d_in[3];
  const float* b_hh1 = (const float*)d_in[4];
  const float* W_ih2 = (const float*)d_in[5];
  // d_in[6] = W_hh2: unused
  const float* b_ih2 = (const float*)d_in[7];
  const float* b_hh2 = (const float*)d_in[8];
  const float* Wp1   = (const float*)d_in[9];
  const float* bp1   = (const float*)d_in[10];
  const float* Wp2   = (const float*)d_in[11];
  const float* bp2   = (const float*)d_in[12];
  const float* W_out = (const float*)d_in[13];
  const float* b_out = (const float*)d_in[14];
  const int* traces  = (const int*)d_in[15];
  const int* lengths = (const int*)d_in[16];

  char* ws = (char*)d_ws;
  u16*   w1b  = (u16*)(ws);                  // 512*64*2   = 65536 B
  u16*   w2b  = (u16*)(ws + 65536);          // 512*128*2  = 131072 B
  u16*   wp1b = (u16*)(ws + 196608);         // 64*128*2   = 16384 B
  float* bs1  = (float*)(ws + 212992);       // 2048 B
  float* bs2  = (float*)(ws + 215040);       // 2048 B
  float* bins = (float*)(ws + 217088);       // 64*128*4   = 32768 B
  u16*   embb = (u16*)(ws + 249856);         // 10000*64*2 = 1280000 B

  k_prep<<<256, 256, 0, stream>>>(emb, W_ih1, W_ih2, Wp1, b_ih1, b_hh1,
                                  b_ih2, b_hh2, embb, w1b, w2b, wp1b,
                                  bs1, bs2, bins);
  k_fused<<<NTRACE, 64, 0, stream>>>(embb, w1b, bs1, w2b, bs2, wp1b,
                                     bp1, Wp2, bp2, traces, lengths, bins);
  k_out<<<1, 128, 0, stream>>>(bins, W_out, b_out, (float*)d_out);
}